// Round 3
// baseline (495.060 us; speedup 1.0000x reference)
//
#include <hip/hip_runtime.h>

#define NPTS 8192
#define BATCH 2
#define CC 64
#define KNN 16

typedef __attribute__((ext_vector_type(4))) float  f32x4;
typedef __attribute__((ext_vector_type(8))) short  s16x8;

__device__ __forceinline__ unsigned short f2bf(float f) {
  unsigned u = __float_as_uint(f);
  unsigned r = ((u >> 16) & 1u) + 0x7FFFu;
  return (unsigned short)((u + r) >> 16);
}

__device__ __forceinline__ float leaky(float v) { return fmaxf(v, 0.1f * v); }

__device__ __forceinline__ s16x8 pack8(const float v[8]) {
  union { s16x8 v8; unsigned short s[8]; } u;
  #pragma unroll
  for (int j = 0; j < 8; ++j) u.s[j] = f2bf(v[j]);
  return u.v8;
}

// ---------------- prep: [B,3,N] -> float4 {x,y,z,|p|^2} ----------------
__global__ __launch_bounds__(256) void kprep(const float* __restrict__ pc1,
                                             const float* __restrict__ pc2,
                                             float4* __restrict__ x1t,
                                             float4* __restrict__ x2t) {
  int i = blockIdx.x * 256 + threadIdx.x;  // [0, B*N)
  int b = i >> 13, n = i & (NPTS - 1);
  size_t base = (size_t)b * 3 * NPTS + n;
  float x = pc1[base], y = pc1[base + NPTS], z = pc1[base + 2 * NPTS];
  x1t[i] = make_float4(x, y, z, x * x + y * y + z * z);
  x = pc2[base]; y = pc2[base + NPTS]; z = pc2[base + 2 * NPTS];
  x2t[i] = make_float4(x, y, z, x * x + y * y + z * z);
}

// ------------- input transforms: out[b,n,m] = sum_c in[b,c,n] W[m,c] + b[m] -------------
__global__ __launch_bounds__(256) void ktrans(
    const float* __restrict__ f1, const float* __restrict__ f2,
    const float* __restrict__ w11, const float* __restrict__ b11,
    const float* __restrict__ w22, const float* __restrict__ b22,
    float* __restrict__ q1, float* __restrict__ q2,
    float* __restrict__ r1, float* __restrict__ r2) {
  const int z = blockIdx.z;
  const float* in = (z == 0 || z == 3) ? f1 : f2;
  const float* W  = (z == 0 || z == 2) ? w11 : w22;
  const float* Bb = (z == 0 || z == 2) ? b11 : b22;
  float* out = (z == 0) ? q1 : (z == 1) ? q2 : (z == 2) ? r1 : r2;
  const int b = blockIdx.y;
  const int n0 = blockIdx.x * 64;
  const int t = threadIdx.x;

  __shared__ float ft[64 * 65];
  __shared__ float wt[64 * 68];

  #pragma unroll
  for (int j = 0; j < 16; ++j) {
    int e = t + 256 * j;
    int c = e >> 6, tn = e & 63;
    ft[c * 65 + tn] = in[((size_t)b * 64 + c) * NPTS + n0 + tn];
  }
  #pragma unroll
  for (int j = 0; j < 16; ++j) {
    int e = t + 256 * j;
    int mm = e >> 6, c = e & 63;
    wt[c * 68 + mm] = W[e];
  }
  __syncthreads();

  const int tn = t & 63, mg = t >> 6;
  float a[16];
  #pragma unroll
  for (int u = 0; u < 4; ++u) {
    float4 bb = *(const float4*)&Bb[16 * mg + 4 * u];
    a[4 * u] = bb.x; a[4 * u + 1] = bb.y; a[4 * u + 2] = bb.z; a[4 * u + 3] = bb.w;
  }
  for (int c = 0; c < 64; ++c) {
    float x = ft[c * 65 + tn];
    #pragma unroll
    for (int u = 0; u < 4; ++u) {
      float4 w4 = *(const float4*)&wt[c * 68 + 16 * mg + 4 * u];
      a[4 * u]     = fmaf(x, w4.x, a[4 * u]);
      a[4 * u + 1] = fmaf(x, w4.y, a[4 * u + 1]);
      a[4 * u + 2] = fmaf(x, w4.z, a[4 * u + 2]);
      a[4 * u + 3] = fmaf(x, w4.w, a[4 * u + 3]);
    }
  }
  size_t ob = ((size_t)b * NPTS + n0 + tn) * 64 + 16 * mg;
  #pragma unroll
  for (int u = 0; u < 4; ++u)
    *(float4*)&out[ob + 4 * u] =
        make_float4(a[4 * u], a[4 * u + 1], a[4 * u + 2], a[4 * u + 3]);
}

// ---------------- KNN phase 1: per-chunk exact top-16 ----------------
__device__ __forceinline__ void kinsert(unsigned key, unsigned ii,
                                        unsigned (&D)[16], unsigned (&I)[16]) {
  if (key < D[15]) {
    bool lt[16];
    #pragma unroll
    for (int j = 0; j < 16; ++j) lt[j] = key < D[j];
    #pragma unroll
    for (int j = 15; j >= 1; --j) {
      D[j] = lt[j - 1] ? D[j - 1] : (lt[j] ? key : D[j]);
      I[j] = lt[j - 1] ? I[j - 1] : (lt[j] ? ii  : I[j]);
    }
    if (lt[0]) { D[0] = key; I[0] = ii; }
  }
}

#define CHUNKS 8
#define CHSZ (NPTS / CHUNKS)  // 1024

__global__ __launch_bounds__(256) void kknn(const float4* __restrict__ x1t,
                                            const float4* __restrict__ x2t,
                                            uint2* __restrict__ part) {
  const int dir = blockIdx.z;
  const int b = blockIdx.y;
  const float4* xq = dir ? x2t : x1t;
  const float4* xc = dir ? x1t : x2t;
  const int t = threadIdx.x;
  const int qb = blockIdx.x & 31;
  const int ck = blockIdx.x >> 5;
  const int qi = qb * 256 + t;  // one query per lane

  __shared__ float4 tile[CHSZ];    // 16 KB, read wave-uniform -> broadcast
  __shared__ uint2 ring[12][256];  // 24 KB, bank = 2t%32

  // stage the whole chunk once
  const float4* src = xc + (size_t)b * NPTS + ck * CHSZ;
  #pragma unroll
  for (int j = 0; j < CHSZ / 256; ++j) tile[j * 256 + t] = src[j * 256 + t];

  float4 Q = xq[(size_t)b * NPTS + qi];
  const float nqx = -2.f * Q.x, nqy = -2.f * Q.y, nqz = -2.f * Q.z, qn = Q.w;

  unsigned D[16], I[16];
  #pragma unroll
  for (int j = 0; j < 16; ++j) { D[j] = 0xFFFFFFFFu; I[j] = 0u; }
  int cnt = 0;

  __syncthreads();

  const unsigned ibase = (unsigned)(ck * CHSZ);
  for (int j0 = 0; j0 < CHSZ; j0 += 8) {
    #pragma unroll
    for (int u = 0; u < 8; ++u) {
      float4 C = tile[j0 + u];  // LDS broadcast (same addr all lanes)
      float d = fmaf(C.x, nqx, fmaf(C.y, nqy, fmaf(C.z, nqz, qn + C.w)));
      unsigned key = (unsigned)max((int)__float_as_uint(d), 0);  // clamp negatives to +0
      if (key < D[15]) { ring[cnt][t] = make_uint2(key, ibase + j0 + u); ++cnt; }
    }
    if (__any(cnt >= 5)) {  // max +8 between checks, depth 12: 4+8 <= 12
      for (int e = 0; e < cnt; ++e) {
        uint2 kv = ring[e][t];
        kinsert(kv.x, kv.y, D, I);
      }
      cnt = 0;
    }
  }
  for (int e = 0; e < cnt; ++e) {
    uint2 kv = ring[e][t];
    kinsert(kv.x, kv.y, D, I);
  }

  // sorted partial list -> part[((g*CHUNKS+ck)*16+j)*NPTS + qi], g=(dir<<1)|b
  uint2* pb = part + ((size_t)(((dir << 1) | b) * CHUNKS + ck) * 16) * NPTS;
  #pragma unroll
  for (int j = 0; j < 16; ++j)
    pb[(size_t)j * NPTS + qi] = make_uint2(D[j], I[j]);
}

// ---------------- KNN phase 2: merge CHUNKS sorted 16-lists per query ----------------
__global__ __launch_bounds__(256) void kmerge(const uint2* __restrict__ part,
                                              int* __restrict__ idx12,
                                              int* __restrict__ idx21) {
  const int dir = blockIdx.z, b = blockIdx.y;
  const int qi = blockIdx.x * 256 + threadIdx.x;
  const uint2* pb = part + ((size_t)(((dir << 1) | b) * CHUNKS) * 16) * NPTS;

  unsigned D[16], I[16];
  #pragma unroll
  for (int j = 0; j < 16; ++j) {
    uint2 kv = pb[(size_t)j * NPTS + qi];
    D[j] = kv.x; I[j] = kv.y;
  }
  for (int ck = 1; ck < CHUNKS; ++ck) {
    #pragma unroll
    for (int j = 0; j < 16; ++j) {
      uint2 kv = pb[(size_t)(ck * 16 + j) * NPTS + qi];
      kinsert(kv.x, kv.y, D, I);
    }
  }
  int* out = dir ? idx21 : idx12;
  size_t ob = ((size_t)b * NPTS + qi) * 16;
  #pragma unroll
  for (int j = 0; j < 16; ++j) out[ob + j] = (int)I[j];
}

// ---------------- fused cross: gather + pos-conv + NL x (64x64 MFMA layer) + maxpool ----------------
template <int NL>
__global__ __launch_bounds__(256) void kcross(
    const float4* __restrict__ xq0, const float4* __restrict__ xc0, const int* __restrict__ idx0,
    const float* __restrict__ p10, const float* __restrict__ p20,
    float* __restrict__ orm0, float* __restrict__ ocn0,
    const float4* __restrict__ xq1, const float4* __restrict__ xc1, const int* __restrict__ idx1,
    const float* __restrict__ p11, const float* __restrict__ p21,
    float* __restrict__ orm1, float* __restrict__ ocn1,
    const float* __restrict__ posw, const float* __restrict__ posb,
    const float* __restrict__ w1, const float* __restrict__ b1,
    const float* __restrict__ w2, const float* __restrict__ b2) {
  const float4* xq; const float4* xc; const int* idx; const float* p1; const float* p2;
  float* orm; float* ocn;
  if (blockIdx.y == 0) { xq = xq0; xc = xc0; idx = idx0; p1 = p10; p2 = p20; orm = orm0; ocn = ocn0; }
  else                 { xq = xq1; xc = xc1; idx = idx1; p1 = p11; p2 = p21; orm = orm1; ocn = ocn1; }

  __shared__ float4 pw4[64];
  __shared__ __align__(16) unsigned short ylds[4][16 * 72];  // per-wave bf16 Y tile, stride 72

  const int t = threadIdx.x;
  const int lane = t & 63;
  const int w = t >> 6;
  const int m = lane & 15;   // A-row (neighbor) / C-col
  const int q = lane >> 4;   // quad

  if (t < 64) pw4[t] = make_float4(posw[t * 3], posw[t * 3 + 1], posw[t * 3 + 2], posb[t]);
  __syncthreads();

  // B-operand frags: B[k][n] = W[n][k]; lane holds W[16ct+m][32kt+8q+j]
  s16x8 wf[2][4][2];
  float bv[2][4];
  #pragma unroll
  for (int l = 0; l < NL; ++l) {
    const float* Wl = l ? w2 : w1;
    const float* Bl = l ? b2 : b1;
    #pragma unroll
    for (int ct = 0; ct < 4; ++ct) {
      bv[l][ct] = Bl[16 * ct + m];
      const float* rowp = Wl + (size_t)(16 * ct + m) * 64;
      #pragma unroll
      for (int kt = 0; kt < 2; ++kt) {
        const float* pp = rowp + 32 * kt + 8 * q;
        float4 A  = *(const float4*)pp;
        float4 Bq = *(const float4*)(pp + 4);
        float vv[8] = {A.x, A.y, A.z, A.w, Bq.x, Bq.y, Bq.z, Bq.w};
        wf[l][ct][kt] = pack8(vv);
      }
    }
  }

  unsigned short* yw = &ylds[w][0];
  const f32x4 zz = {0.f, 0.f, 0.f, 0.f};

  #pragma unroll 1
  for (int i = 0; i < 4; ++i) {
    int gp = blockIdx.x * 16 + w * 4 + i;
    int b = gp >> 13, n = gp & (NPTS - 1);
    size_t qb = (size_t)b * NPTS + n;
    int nb = idx[qb * 16 + m];
    size_t cb = (size_t)b * NPTS + nb;
    float4 qp  = xq[qb];
    float4 nbp = xc[cb];
    float dx = nbp.x - qp.x, dy = nbp.y - qp.y, dz = nbp.z - qp.z;

    // build A-frags: X[m][c] = leaky(g2 + p1 + dir.posw + posb), c = 32h + 8q + j
    s16x8 af[2];
    #pragma unroll
    for (int h = 0; h < 2; ++h) {
      int c0 = 32 * h + 8 * q;
      const float* g2p = p2 + cb * 64 + c0;
      float4 ga = *(const float4*)g2p;
      float4 gb = *(const float4*)(g2p + 4);
      const float* p1p = p1 + qb * 64 + c0;
      float4 pa = *(const float4*)p1p;
      float4 pb = *(const float4*)(p1p + 4);
      float gg[8] = {ga.x + pa.x, ga.y + pa.y, ga.z + pa.z, ga.w + pa.w,
                     gb.x + pb.x, gb.y + pb.y, gb.z + pb.z, gb.w + pb.w};
      float vv[8];
      #pragma unroll
      for (int j = 0; j < 8; ++j) {
        float4 pw = pw4[c0 + j];
        float v = gg[j] + pw.w;
        v = fmaf(dx, pw.x, v);
        v = fmaf(dy, pw.y, v);
        v = fmaf(dz, pw.z, v);
        vv[j] = leaky(v);
      }
      af[h] = pack8(vv);
    }

    f32x4 acc[4];
    #pragma unroll
    for (int ct = 0; ct < 4; ++ct) {
      acc[ct] = __builtin_amdgcn_mfma_f32_16x16x32_bf16(af[0], wf[0][ct][0], zz, 0, 0, 0);
      acc[ct] = __builtin_amdgcn_mfma_f32_16x16x32_bf16(af[1], wf[0][ct][1], acc[ct], 0, 0, 0);
    }
    float y[4][4];
    #pragma unroll
    for (int ct = 0; ct < 4; ++ct)
      #pragma unroll
      for (int r = 0; r < 4; ++r)
        y[ct][r] = leaky(acc[ct][r] + bv[0][ct]);

    if (NL == 2) {
      // C-layout -> A-layout transition via per-wave LDS tile (bf16); wave-scope ordering only
      #pragma unroll
      for (int ct = 0; ct < 4; ++ct)
        #pragma unroll
        for (int r = 0; r < 4; ++r)
          yw[(q * 4 + r) * 72 + 16 * ct + m] = f2bf(y[ct][r]);
      asm volatile("s_waitcnt lgkmcnt(0)" ::: "memory");
      s16x8 a2[2];
      a2[0] = *(const s16x8*)(yw + m * 72 + 8 * q);
      a2[1] = *(const s16x8*)(yw + m * 72 + 32 + 8 * q);
      #pragma unroll
      for (int ct = 0; ct < 4; ++ct) {
        acc[ct] = __builtin_amdgcn_mfma_f32_16x16x32_bf16(a2[0], wf[1][ct][0], zz, 0, 0, 0);
        acc[ct] = __builtin_amdgcn_mfma_f32_16x16x32_bf16(a2[1], wf[1][ct][1], acc[ct], 0, 0, 0);
      }
      #pragma unroll
      for (int ct = 0; ct < 4; ++ct)
        #pragma unroll
        for (int r = 0; r < 4; ++r)
          y[ct][r] = leaky(acc[ct][r] + bv[1][ct]);
      asm volatile("s_waitcnt lgkmcnt(0)" ::: "memory");  // reads retired before next iter's writes
    }

    // maxpool over 16 neighbors (rows): in-lane over 4 regs, then across quads
    float pm[4];
    #pragma unroll
    for (int ct = 0; ct < 4; ++ct) {
      float v = fmaxf(fmaxf(y[ct][0], y[ct][1]), fmaxf(y[ct][2], y[ct][3]));
      v = fmaxf(v, __shfl_xor(v, 16));
      v = fmaxf(v, __shfl_xor(v, 32));
      pm[ct] = v;
    }
    float sel = (q == 0) ? pm[0] : (q == 1) ? pm[1] : (q == 2) ? pm[2] : pm[3];  // col 16q+m == lane
    if (orm) orm[qb * 64 + lane] = sel;
    if (ocn) ocn[((size_t)b * 64 + lane) * NPTS + n] = sel;
  }
}

// ---------------- post: fn = pool @ tW^T + tb ; write row-major + transposed ----------------
__global__ __launch_bounds__(256) void kpost(
    const float* __restrict__ inA, const float* __restrict__ inB,
    const float* __restrict__ wA, const float* __restrict__ bA,
    const float* __restrict__ wB, const float* __restrict__ bB,
    float* __restrict__ frA, float* __restrict__ frB,
    float* __restrict__ cnA, float* __restrict__ cnB) {
  const int z = blockIdx.z;
  const float* in = z ? inB : inA;
  const float* W  = z ? wB : wA;
  const float* Bb = z ? bB : bA;
  float* fr = z ? frB : frA;
  float* cn = z ? cnB : cnA;
  const int b = blockIdx.y;
  const int n0 = blockIdx.x * 64;
  const int t = threadIdx.x;

  __shared__ float pl[64 * 65];
  __shared__ float wt[64 * 68];

  #pragma unroll
  for (int j = 0; j < 16; ++j) {
    int e = t + 256 * j;
    int r = e >> 6, c = e & 63;
    pl[r * 65 + c] = in[((size_t)b * NPTS + n0 + r) * 64 + c];
  }
  #pragma unroll
  for (int j = 0; j < 16; ++j) {
    int e = t + 256 * j;
    int mm = e >> 6, c = e & 63;
    wt[c * 68 + mm] = W[e];
  }
  __syncthreads();

  const int tn = t & 63, mg = t >> 6;
  float a[16];
  #pragma unroll
  for (int u = 0; u < 4; ++u) {
    float4 bb = *(const float4*)&Bb[16 * mg + 4 * u];
    a[4 * u] = bb.x; a[4 * u + 1] = bb.y; a[4 * u + 2] = bb.z; a[4 * u + 3] = bb.w;
  }
  for (int c = 0; c < 64; ++c) {
    float x = pl[tn * 65 + c];
    #pragma unroll
    for (int u = 0; u < 4; ++u) {
      float4 w4 = *(const float4*)&wt[c * 68 + 16 * mg + 4 * u];
      a[4 * u]     = fmaf(x, w4.x, a[4 * u]);
      a[4 * u + 1] = fmaf(x, w4.y, a[4 * u + 1]);
      a[4 * u + 2] = fmaf(x, w4.z, a[4 * u + 2]);
      a[4 * u + 3] = fmaf(x, w4.w, a[4 * u + 3]);
    }
  }
  size_t ob = ((size_t)b * NPTS + n0 + tn) * 64 + 16 * mg;
  #pragma unroll
  for (int u = 0; u < 4; ++u)
    *(float4*)&fr[ob + 4 * u] =
        make_float4(a[4 * u], a[4 * u + 1], a[4 * u + 2], a[4 * u + 3]);
  #pragma unroll
  for (int jj = 0; jj < 16; ++jj) {
    int mo = 16 * mg + jj;
    cn[((size_t)b * 64 + mo) * NPTS + n0 + tn] = a[jj];
  }
}

extern "C" void kernel_launch(void* const* d_in, const int* in_sizes, int n_in,
                              void* d_out, int out_size, void* d_ws, size_t ws_size,
                              hipStream_t stream) {
  const float* pc1   = (const float*)d_in[0];
  const float* pc2   = (const float*)d_in[1];
  const float* feat1 = (const float*)d_in[2];
  const float* feat2 = (const float*)d_in[3];
  const float* t11w  = (const float*)d_in[4];
  const float* t11b  = (const float*)d_in[5];
  const float* t22w  = (const float*)d_in[6];
  const float* t22b  = (const float*)d_in[7];
  const float* pos1w = (const float*)d_in[8];
  const float* pos1b = (const float*)d_in[9];
  const float* m1w1  = (const float*)d_in[10];
  const float* m1b1  = (const float*)d_in[11];
  const float* m1w2  = (const float*)d_in[12];
  const float* m1b2  = (const float*)d_in[13];
  const float* t1w   = (const float*)d_in[14];
  const float* t1b   = (const float*)d_in[15];
  const float* t2w   = (const float*)d_in[16];
  const float* t2b   = (const float*)d_in[17];
  const float* pos2w = (const float*)d_in[18];
  const float* pos2b = (const float*)d_in[19];
  const float* m2w1  = (const float*)d_in[20];
  const float* m2b1  = (const float*)d_in[21];

  char* ws = (char*)d_ws;
  size_t off = 0;
  auto take = [&](size_t bytes) {
    char* p = ws + off;
    off += (bytes + 255) & ~(size_t)255;
    return p;
  };
  float4* x1t  = (float4*)take((size_t)BATCH * NPTS * sizeof(float4));
  float4* x2t  = (float4*)take((size_t)BATCH * NPTS * sizeof(float4));
  int* idx12   = (int*)take((size_t)BATCH * NPTS * KNN * 4);
  int* idx21   = (int*)take((size_t)BATCH * NPTS * KNN * 4);
  // 32 MB contiguous region; `part` (33.5 MB) aliases it + 2 MB pad.
  // Lifetime safe: kknn writes part, kmerge reads it, BOTH run before
  // ktrans/kcross/kpost write q1..fn2 (same stream => ordered).
  float* q1    = (float*)take((size_t)BATCH * NPTS * CC * 4);
  float* q2    = (float*)take((size_t)BATCH * NPTS * CC * 4);
  float* r1    = (float*)take((size_t)BATCH * NPTS * CC * 4);
  float* r2    = (float*)take((size_t)BATCH * NPTS * CC * 4);
  float* poolA = (float*)take((size_t)BATCH * NPTS * CC * 4);
  float* poolB = (float*)take((size_t)BATCH * NPTS * CC * 4);
  float* fn1   = (float*)take((size_t)BATCH * NPTS * CC * 4);
  float* fn2   = (float*)take((size_t)BATCH * NPTS * CC * 4);
  take((size_t)2 * 1024 * 1024);  // pad so part fits
  uint2* part  = (uint2*)q1;      // 4*CHUNKS*16*NPTS*8 = 33.5 MB

  float* out = (float*)d_out;
  size_t seg = (size_t)BATCH * CC * NPTS;

  kprep<<<dim3(BATCH * NPTS / 256), 256, 0, stream>>>(pc1, pc2, x1t, x2t);
  kknn<<<dim3(32 * CHUNKS, BATCH, 2), 256, 0, stream>>>(x1t, x2t, part);
  kmerge<<<dim3(NPTS / 256, BATCH, 2), 256, 0, stream>>>(part, idx12, idx21);
  ktrans<<<dim3(NPTS / 64, BATCH, 4), 256, 0, stream>>>(
      feat1, feat2, t11w, t11b, t22w, t22b, q1, q2, r1, r2);
  kcross<2><<<dim3(1024, 2), 256, 0, stream>>>(
      x1t, x2t, idx12, q1, q2, poolA, (float*)nullptr,
      x2t, x1t, idx21, r1, r2, poolB, (float*)nullptr,
      pos1w, pos1b, m1w1, m1b1, m1w2, m1b2);
  kpost<<<dim3(NPTS / 64, BATCH, 2), 256, 0, stream>>>(
      poolA, poolB, t1w, t1b, t2w, t2b, fn1, fn2, out, out + seg);
  kcross<1><<<dim3(1024, 1), 256, 0, stream>>>(
      x1t, x2t, idx12, fn1, fn2, (float*)nullptr, out + 2 * seg,
      x1t, x2t, idx12, fn1, fn2, (float*)nullptr, (float*)nullptr,
      pos2w, pos2b, m2w1, m2b1, m2w1, m2b1);
}

// Round 4
// 462.626 us; speedup vs baseline: 1.0701x; 1.0701x over previous
//
#include <hip/hip_runtime.h>

#define NPTS 8192
#define BATCH 2
#define CC 64
#define KNN 16

typedef __attribute__((ext_vector_type(4))) float  f32x4;
typedef __attribute__((ext_vector_type(8))) short  s16x8;

__device__ __forceinline__ unsigned short f2bf(float f) {
  unsigned u = __float_as_uint(f);
  unsigned r = ((u >> 16) & 1u) + 0x7FFFu;
  return (unsigned short)((u + r) >> 16);
}

__device__ __forceinline__ float leaky(float v) { return fmaxf(v, 0.1f * v); }

__device__ __forceinline__ s16x8 pack8(const float v[8]) {
  union { s16x8 v8; unsigned short s[8]; } u;
  #pragma unroll
  for (int j = 0; j < 8; ++j) u.s[j] = f2bf(v[j]);
  return u.v8;
}

// ---------------- prep: [B,3,N] -> float4 {x,y,z,|p|^2} ----------------
__global__ __launch_bounds__(256) void kprep(const float* __restrict__ pc1,
                                             const float* __restrict__ pc2,
                                             float4* __restrict__ x1t,
                                             float4* __restrict__ x2t) {
  int i = blockIdx.x * 256 + threadIdx.x;  // [0, B*N)
  int b = i >> 13, n = i & (NPTS - 1);
  size_t base = (size_t)b * 3 * NPTS + n;
  float x = pc1[base], y = pc1[base + NPTS], z = pc1[base + 2 * NPTS];
  x1t[i] = make_float4(x, y, z, x * x + y * y + z * z);
  x = pc2[base]; y = pc2[base + NPTS]; z = pc2[base + 2 * NPTS];
  x2t[i] = make_float4(x, y, z, x * x + y * y + z * z);
}

// ------------- input transforms: out[b,n,m] = sum_c in[b,c,n] W[m,c] + b[m] -------------
__global__ __launch_bounds__(256) void ktrans(
    const float* __restrict__ f1, const float* __restrict__ f2,
    const float* __restrict__ w11, const float* __restrict__ b11,
    const float* __restrict__ w22, const float* __restrict__ b22,
    float* __restrict__ q1, float* __restrict__ q2,
    float* __restrict__ r1, float* __restrict__ r2) {
  const int z = blockIdx.z;
  const float* in = (z == 0 || z == 3) ? f1 : f2;
  const float* W  = (z == 0 || z == 2) ? w11 : w22;
  const float* Bb = (z == 0 || z == 2) ? b11 : b22;
  float* out = (z == 0) ? q1 : (z == 1) ? q2 : (z == 2) ? r1 : r2;
  const int b = blockIdx.y;
  const int n0 = blockIdx.x * 64;
  const int t = threadIdx.x;

  __shared__ float ft[64 * 65];
  __shared__ float wt[64 * 68];

  #pragma unroll
  for (int j = 0; j < 16; ++j) {
    int e = t + 256 * j;
    int c = e >> 6, tn = e & 63;
    ft[c * 65 + tn] = in[((size_t)b * 64 + c) * NPTS + n0 + tn];
  }
  #pragma unroll
  for (int j = 0; j < 16; ++j) {
    int e = t + 256 * j;
    int mm = e >> 6, c = e & 63;
    wt[c * 68 + mm] = W[e];
  }
  __syncthreads();

  const int tn = t & 63, mg = t >> 6;
  float a[16];
  #pragma unroll
  for (int u = 0; u < 4; ++u) {
    float4 bb = *(const float4*)&Bb[16 * mg + 4 * u];
    a[4 * u] = bb.x; a[4 * u + 1] = bb.y; a[4 * u + 2] = bb.z; a[4 * u + 3] = bb.w;
  }
  for (int c = 0; c < 64; ++c) {
    float x = ft[c * 65 + tn];
    #pragma unroll
    for (int u = 0; u < 4; ++u) {
      float4 w4 = *(const float4*)&wt[c * 68 + 16 * mg + 4 * u];
      a[4 * u]     = fmaf(x, w4.x, a[4 * u]);
      a[4 * u + 1] = fmaf(x, w4.y, a[4 * u + 1]);
      a[4 * u + 2] = fmaf(x, w4.z, a[4 * u + 2]);
      a[4 * u + 3] = fmaf(x, w4.w, a[4 * u + 3]);
    }
  }
  size_t ob = ((size_t)b * NPTS + n0 + tn) * 64 + 16 * mg;
  #pragma unroll
  for (int u = 0; u < 4; ++u)
    *(float4*)&out[ob + 4 * u] =
        make_float4(a[4 * u], a[4 * u + 1], a[4 * u + 2], a[4 * u + 3]);
}

// ---------------- KNN phase 1: per-chunk exact top-16 ----------------
__device__ __forceinline__ void kinsert(unsigned key, unsigned ii,
                                        unsigned (&D)[16], unsigned (&I)[16]) {
  if (key < D[15]) {
    bool lt[16];
    #pragma unroll
    for (int j = 0; j < 16; ++j) lt[j] = key < D[j];
    #pragma unroll
    for (int j = 15; j >= 1; --j) {
      D[j] = lt[j - 1] ? D[j - 1] : (lt[j] ? key : D[j]);
      I[j] = lt[j - 1] ? I[j - 1] : (lt[j] ? ii  : I[j]);
    }
    if (lt[0]) { D[0] = key; I[0] = ii; }
  }
}

#define CHUNKS 8
#define CHSZ (NPTS / CHUNKS)  // 1024
#define RDEPTH 28
#define RTRIG 20

__global__ __launch_bounds__(256) void kknn(const float4* __restrict__ x1t,
                                            const float4* __restrict__ x2t,
                                            uint2* __restrict__ part) {
  const int dir = blockIdx.z;
  const int b = blockIdx.y;
  const float4* xq = dir ? x2t : x1t;
  const float4* xc = dir ? x1t : x2t;
  const int t = threadIdx.x;
  const int qb = blockIdx.x & 31;
  const int ck = blockIdx.x >> 5;
  const int qi = qb * 256 + t;  // one query per lane

  __shared__ float4 tile[CHSZ];                 // 16 KB, wave-uniform reads -> broadcast
  __shared__ unsigned short ring[RDEPTH][256];  // 14 KB, within-chunk idx only

  // stage the whole chunk once
  const float4* src = xc + (size_t)b * NPTS + ck * CHSZ;
  #pragma unroll
  for (int j = 0; j < CHSZ / 256; ++j) tile[j * 256 + t] = src[j * 256 + t];

  float4 Q = xq[(size_t)b * NPTS + qi];
  const float nqx = -2.f * Q.x, nqy = -2.f * Q.y, nqz = -2.f * Q.z, qn = Q.w;

  unsigned D[16], I[16];
  #pragma unroll
  for (int j = 0; j < 16; ++j) { D[j] = 0xFFFFFFFFu; I[j] = 0u; }
  int cnt = 0;

  __syncthreads();

  const unsigned ibase = (unsigned)(ck * CHSZ);
  for (int j0 = 0; j0 < CHSZ; j0 += 8) {
    unsigned D15 = D[15];
    #pragma unroll
    for (int u = 0; u < 8; ++u) {
      float4 C = tile[j0 + u];  // LDS broadcast (same addr all lanes)
      float d = fmaf(C.x, nqx, fmaf(C.y, nqy, fmaf(C.z, nqz, qn + C.w)));
      unsigned key = (unsigned)max((int)__float_as_uint(d), 0);  // clamp negatives to +0
      ring[cnt][t] = (unsigned short)(j0 + u);  // unconditional write to slot cnt
      cnt += (key < D15) ? 1 : 0;               // advance only on survivor
    }
    if (__any(cnt >= RTRIG)) {  // max +8 between checks: 19+8 <= 28
      for (int e = 0; e < cnt; ++e) {
        int ji = ring[e][t];
        float4 C = tile[ji];
        float d = fmaf(C.x, nqx, fmaf(C.y, nqy, fmaf(C.z, nqz, qn + C.w)));
        unsigned key = (unsigned)max((int)__float_as_uint(d), 0);
        kinsert(key, ibase + ji, D, I);  // internal key<D[15] guard drops stale
      }
      cnt = 0;
    }
  }
  for (int e = 0; e < cnt; ++e) {
    int ji = ring[e][t];
    float4 C = tile[ji];
    float d = fmaf(C.x, nqx, fmaf(C.y, nqy, fmaf(C.z, nqz, qn + C.w)));
    unsigned key = (unsigned)max((int)__float_as_uint(d), 0);
    kinsert(key, ibase + ji, D, I);
  }

  // sorted partial list -> part[((g*CHUNKS+ck)*16+j)*NPTS + qi], g=(dir<<1)|b
  uint2* pb = part + ((size_t)(((dir << 1) | b) * CHUNKS + ck) * 16) * NPTS;
  #pragma unroll
  for (int j = 0; j < 16; ++j)
    pb[(size_t)j * NPTS + qi] = make_uint2(D[j], I[j]);
}

// ---------------- KNN phase 2: merge CHUNKS sorted 16-lists per query ----------------
__global__ __launch_bounds__(256) void kmerge(const uint2* __restrict__ part,
                                              int* __restrict__ idx12,
                                              int* __restrict__ idx21) {
  const int dir = blockIdx.z, b = blockIdx.y;
  const int qi = blockIdx.x * 256 + threadIdx.x;
  const uint2* pb = part + ((size_t)(((dir << 1) | b) * CHUNKS) * 16) * NPTS;

  unsigned D[16], I[16];
  #pragma unroll
  for (int j = 0; j < 16; ++j) {
    uint2 kv = pb[(size_t)j * NPTS + qi];
    D[j] = kv.x; I[j] = kv.y;
  }
  for (int ck = 1; ck < CHUNKS; ++ck) {
    #pragma unroll
    for (int j = 0; j < 16; ++j) {
      uint2 kv = pb[(size_t)(ck * 16 + j) * NPTS + qi];
      kinsert(kv.x, kv.y, D, I);
    }
  }
  int* out = dir ? idx21 : idx12;
  size_t ob = ((size_t)b * NPTS + qi) * 16;
  #pragma unroll
  for (int j = 0; j < 16; ++j) out[ob + j] = (int)I[j];
}

// ---------------- fused cross: gather + pos-conv + NL x (64x64 MFMA layer) + maxpool ----------------
template <int NL>
__global__ __launch_bounds__(256) void kcross(
    const float4* __restrict__ xq0, const float4* __restrict__ xc0, const int* __restrict__ idx0,
    const float* __restrict__ p10, const float* __restrict__ p20,
    float* __restrict__ orm0, float* __restrict__ ocn0,
    const float4* __restrict__ xq1, const float4* __restrict__ xc1, const int* __restrict__ idx1,
    const float* __restrict__ p11, const float* __restrict__ p21,
    float* __restrict__ orm1, float* __restrict__ ocn1,
    const float* __restrict__ posw, const float* __restrict__ posb,
    const float* __restrict__ w1, const float* __restrict__ b1,
    const float* __restrict__ w2, const float* __restrict__ b2) {
  const float4* xq; const float4* xc; const int* idx; const float* p1; const float* p2;
  float* orm; float* ocn;
  if (blockIdx.y == 0) { xq = xq0; xc = xc0; idx = idx0; p1 = p10; p2 = p20; orm = orm0; ocn = ocn0; }
  else                 { xq = xq1; xc = xc1; idx = idx1; p1 = p11; p2 = p21; orm = orm1; ocn = ocn1; }

  __shared__ float4 pw4[64];
  __shared__ __align__(16) unsigned short ylds[4][16 * 72];  // per-wave bf16 Y tile, stride 72

  const int t = threadIdx.x;
  const int lane = t & 63;
  const int w = t >> 6;
  const int m = lane & 15;   // A-row (neighbor) / C-col
  const int q = lane >> 4;   // quad

  if (t < 64) pw4[t] = make_float4(posw[t * 3], posw[t * 3 + 1], posw[t * 3 + 2], posb[t]);
  __syncthreads();

  // B-operand frags: B[k][n] = W[n][k]; lane holds W[16ct+m][32kt+8q+j]
  s16x8 wf[2][4][2];
  float bv[2][4];
  #pragma unroll
  for (int l = 0; l < NL; ++l) {
    const float* Wl = l ? w2 : w1;
    const float* Bl = l ? b2 : b1;
    #pragma unroll
    for (int ct = 0; ct < 4; ++ct) {
      bv[l][ct] = Bl[16 * ct + m];
      const float* rowp = Wl + (size_t)(16 * ct + m) * 64;
      #pragma unroll
      for (int kt = 0; kt < 2; ++kt) {
        const float* pp = rowp + 32 * kt + 8 * q;
        float4 A  = *(const float4*)pp;
        float4 Bq = *(const float4*)(pp + 4);
        float vv[8] = {A.x, A.y, A.z, A.w, Bq.x, Bq.y, Bq.z, Bq.w};
        wf[l][ct][kt] = pack8(vv);
      }
    }
  }

  unsigned short* yw = &ylds[w][0];
  const f32x4 zz = {0.f, 0.f, 0.f, 0.f};

  #pragma unroll 1
  for (int i = 0; i < 4; ++i) {
    int gp = blockIdx.x * 16 + w * 4 + i;
    int b = gp >> 13, n = gp & (NPTS - 1);
    size_t qb = (size_t)b * NPTS + n;
    int nb = idx[qb * 16 + m];
    size_t cb = (size_t)b * NPTS + nb;
    float4 qp  = xq[qb];
    float4 nbp = xc[cb];
    float dx = nbp.x - qp.x, dy = nbp.y - qp.y, dz = nbp.z - qp.z;

    // build A-frags: X[m][c] = leaky(g2 + p1 + dir.posw + posb), c = 32h + 8q + j
    s16x8 af[2];
    #pragma unroll
    for (int h = 0; h < 2; ++h) {
      int c0 = 32 * h + 8 * q;
      const float* g2p = p2 + cb * 64 + c0;
      float4 ga = *(const float4*)g2p;
      float4 gb = *(const float4*)(g2p + 4);
      const float* p1p = p1 + qb * 64 + c0;
      float4 pa = *(const float4*)p1p;
      float4 pb = *(const float4*)(p1p + 4);
      float gg[8] = {ga.x + pa.x, ga.y + pa.y, ga.z + pa.z, ga.w + pa.w,
                     gb.x + pb.x, gb.y + pb.y, gb.z + pb.z, gb.w + pb.w};
      float vv[8];
      #pragma unroll
      for (int j = 0; j < 8; ++j) {
        float4 pw = pw4[c0 + j];
        float v = gg[j] + pw.w;
        v = fmaf(dx, pw.x, v);
        v = fmaf(dy, pw.y, v);
        v = fmaf(dz, pw.z, v);
        vv[j] = leaky(v);
      }
      af[h] = pack8(vv);
    }

    f32x4 acc[4];
    #pragma unroll
    for (int ct = 0; ct < 4; ++ct) {
      acc[ct] = __builtin_amdgcn_mfma_f32_16x16x32_bf16(af[0], wf[0][ct][0], zz, 0, 0, 0);
      acc[ct] = __builtin_amdgcn_mfma_f32_16x16x32_bf16(af[1], wf[0][ct][1], acc[ct], 0, 0, 0);
    }
    float y[4][4];
    #pragma unroll
    for (int ct = 0; ct < 4; ++ct)
      #pragma unroll
      for (int r = 0; r < 4; ++r)
        y[ct][r] = leaky(acc[ct][r] + bv[0][ct]);

    if (NL == 2) {
      // C-layout -> A-layout transition via per-wave LDS tile (bf16); wave-scope ordering only
      #pragma unroll
      for (int ct = 0; ct < 4; ++ct)
        #pragma unroll
        for (int r = 0; r < 4; ++r)
          yw[(q * 4 + r) * 72 + 16 * ct + m] = f2bf(y[ct][r]);
      asm volatile("s_waitcnt lgkmcnt(0)" ::: "memory");
      s16x8 a2[2];
      a2[0] = *(const s16x8*)(yw + m * 72 + 8 * q);
      a2[1] = *(const s16x8*)(yw + m * 72 + 32 + 8 * q);
      #pragma unroll
      for (int ct = 0; ct < 4; ++ct) {
        acc[ct] = __builtin_amdgcn_mfma_f32_16x16x32_bf16(a2[0], wf[1][ct][0], zz, 0, 0, 0);
        acc[ct] = __builtin_amdgcn_mfma_f32_16x16x32_bf16(a2[1], wf[1][ct][1], acc[ct], 0, 0, 0);
      }
      #pragma unroll
      for (int ct = 0; ct < 4; ++ct)
        #pragma unroll
        for (int r = 0; r < 4; ++r)
          y[ct][r] = leaky(acc[ct][r] + bv[1][ct]);
      asm volatile("s_waitcnt lgkmcnt(0)" ::: "memory");  // reads retired before next iter's writes
    }

    // maxpool over 16 neighbors (rows): in-lane over 4 regs, then across quads
    float pm[4];
    #pragma unroll
    for (int ct = 0; ct < 4; ++ct) {
      float v = fmaxf(fmaxf(y[ct][0], y[ct][1]), fmaxf(y[ct][2], y[ct][3]));
      v = fmaxf(v, __shfl_xor(v, 16));
      v = fmaxf(v, __shfl_xor(v, 32));
      pm[ct] = v;
    }
    float sel = (q == 0) ? pm[0] : (q == 1) ? pm[1] : (q == 2) ? pm[2] : pm[3];  // col 16q+m == lane
    if (orm) orm[qb * 64 + lane] = sel;
    if (ocn) ocn[((size_t)b * 64 + lane) * NPTS + n] = sel;
  }
}

// ---------------- post: fn = pool @ tW^T + tb ; write row-major + transposed ----------------
__global__ __launch_bounds__(256) void kpost(
    const float* __restrict__ inA, const float* __restrict__ inB,
    const float* __restrict__ wA, const float* __restrict__ bA,
    const float* __restrict__ wB, const float* __restrict__ bB,
    float* __restrict__ frA, float* __restrict__ frB,
    float* __restrict__ cnA, float* __restrict__ cnB) {
  const int z = blockIdx.z;
  const float* in = z ? inB : inA;
  const float* W  = z ? wB : wA;
  const float* Bb = z ? bB : bA;
  float* fr = z ? frB : frA;
  float* cn = z ? cnB : cnA;
  const int b = blockIdx.y;
  const int n0 = blockIdx.x * 64;
  const int t = threadIdx.x;

  __shared__ float pl[64 * 65];
  __shared__ float wt[64 * 68];

  #pragma unroll
  for (int j = 0; j < 16; ++j) {
    int e = t + 256 * j;
    int r = e >> 6, c = e & 63;
    pl[r * 65 + c] = in[((size_t)b * NPTS + n0 + r) * 64 + c];
  }
  #pragma unroll
  for (int j = 0; j < 16; ++j) {
    int e = t + 256 * j;
    int mm = e >> 6, c = e & 63;
    wt[c * 68 + mm] = W[e];
  }
  __syncthreads();

  const int tn = t & 63, mg = t >> 6;
  float a[16];
  #pragma unroll
  for (int u = 0; u < 4; ++u) {
    float4 bb = *(const float4*)&Bb[16 * mg + 4 * u];
    a[4 * u] = bb.x; a[4 * u + 1] = bb.y; a[4 * u + 2] = bb.z; a[4 * u + 3] = bb.w;
  }
  for (int c = 0; c < 64; ++c) {
    float x = pl[tn * 65 + c];
    #pragma unroll
    for (int u = 0; u < 4; ++u) {
      float4 w4 = *(const float4*)&wt[c * 68 + 16 * mg + 4 * u];
      a[4 * u]     = fmaf(x, w4.x, a[4 * u]);
      a[4 * u + 1] = fmaf(x, w4.y, a[4 * u + 1]);
      a[4 * u + 2] = fmaf(x, w4.z, a[4 * u + 2]);
      a[4 * u + 3] = fmaf(x, w4.w, a[4 * u + 3]);
    }
  }
  size_t ob = ((size_t)b * NPTS + n0 + tn) * 64 + 16 * mg;
  #pragma unroll
  for (int u = 0; u < 4; ++u)
    *(float4*)&fr[ob + 4 * u] =
        make_float4(a[4 * u], a[4 * u + 1], a[4 * u + 2], a[4 * u + 3]);
  #pragma unroll
  for (int jj = 0; jj < 16; ++jj) {
    int mo = 16 * mg + jj;
    cn[((size_t)b * 64 + mo) * NPTS + n0 + tn] = a[jj];
  }
}

extern "C" void kernel_launch(void* const* d_in, const int* in_sizes, int n_in,
                              void* d_out, int out_size, void* d_ws, size_t ws_size,
                              hipStream_t stream) {
  const float* pc1   = (const float*)d_in[0];
  const float* pc2   = (const float*)d_in[1];
  const float* feat1 = (const float*)d_in[2];
  const float* feat2 = (const float*)d_in[3];
  const float* t11w  = (const float*)d_in[4];
  const float* t11b  = (const float*)d_in[5];
  const float* t22w  = (const float*)d_in[6];
  const float* t22b  = (const float*)d_in[7];
  const float* pos1w = (const float*)d_in[8];
  const float* pos1b = (const float*)d_in[9];
  const float* m1w1  = (const float*)d_in[10];
  const float* m1b1  = (const float*)d_in[11];
  const float* m1w2  = (const float*)d_in[12];
  const float* m1b2  = (const float*)d_in[13];
  const float* t1w   = (const float*)d_in[14];
  const float* t1b   = (const float*)d_in[15];
  const float* t2w   = (const float*)d_in[16];
  const float* t2b   = (const float*)d_in[17];
  const float* pos2w = (const float*)d_in[18];
  const float* pos2b = (const float*)d_in[19];
  const float* m2w1  = (const float*)d_in[20];
  const float* m2b1  = (const float*)d_in[21];

  char* ws = (char*)d_ws;
  size_t off = 0;
  auto take = [&](size_t bytes) {
    char* p = ws + off;
    off += (bytes + 255) & ~(size_t)255;
    return p;
  };
  float4* x1t  = (float4*)take((size_t)BATCH * NPTS * sizeof(float4));
  float4* x2t  = (float4*)take((size_t)BATCH * NPTS * sizeof(float4));
  int* idx12   = (int*)take((size_t)BATCH * NPTS * KNN * 4);
  int* idx21   = (int*)take((size_t)BATCH * NPTS * KNN * 4);
  // 32 MB contiguous region; `part` (33.5 MB) aliases it + 2 MB pad.
  // Lifetime safe: kknn writes part, kmerge reads it, BOTH run before
  // ktrans/kcross/kpost write q1..fn2 (same stream => ordered).
  float* q1    = (float*)take((size_t)BATCH * NPTS * CC * 4);
  float* q2    = (float*)take((size_t)BATCH * NPTS * CC * 4);
  float* r1    = (float*)take((size_t)BATCH * NPTS * CC * 4);
  float* r2    = (float*)take((size_t)BATCH * NPTS * CC * 4);
  float* poolA = (float*)take((size_t)BATCH * NPTS * CC * 4);
  float* poolB = (float*)take((size_t)BATCH * NPTS * CC * 4);
  float* fn1   = (float*)take((size_t)BATCH * NPTS * CC * 4);
  float* fn2   = (float*)take((size_t)BATCH * NPTS * CC * 4);
  take((size_t)2 * 1024 * 1024);  // pad so part fits
  uint2* part  = (uint2*)q1;      // 4*CHUNKS*16*NPTS*8 = 33.5 MB

  float* out = (float*)d_out;
  size_t seg = (size_t)BATCH * CC * NPTS;

  kprep<<<dim3(BATCH * NPTS / 256), 256, 0, stream>>>(pc1, pc2, x1t, x2t);
  kknn<<<dim3(32 * CHUNKS, BATCH, 2), 256, 0, stream>>>(x1t, x2t, part);
  kmerge<<<dim3(NPTS / 256, BATCH, 2), 256, 0, stream>>>(part, idx12, idx21);
  ktrans<<<dim3(NPTS / 64, BATCH, 4), 256, 0, stream>>>(
      feat1, feat2, t11w, t11b, t22w, t22b, q1, q2, r1, r2);
  kcross<2><<<dim3(1024, 2), 256, 0, stream>>>(
      x1t, x2t, idx12, q1, q2, poolA, (float*)nullptr,
      x2t, x1t, idx21, r1, r2, poolB, (float*)nullptr,
      pos1w, pos1b, m1w1, m1b1, m1w2, m1b2);
  kpost<<<dim3(NPTS / 64, BATCH, 2), 256, 0, stream>>>(
      poolA, poolB, t1w, t1b, t2w, t2b, fn1, fn2, out, out + seg);
  kcross<1><<<dim3(1024, 1), 256, 0, stream>>>(
      x1t, x2t, idx12, fn1, fn2, (float*)nullptr, out + 2 * seg,
      x1t, x2t, idx12, fn1, fn2, (float*)nullptr, (float*)nullptr,
      pos2w, pos2b, m2w1, m2b1, m2w1, m2b1);
}